// Round 11
// baseline (157.862 us; speedup 1.0000x reference)
//
#include <hip/hip_runtime.h>
#include <hip/hip_bf16.h>

// cross_set_score — producer/consumer wave specialization.
// x[64,64,64,256] f32. out[p,q]=out[q,p]= sum_h W2[h]*0.125*relu-sum(hA·hB^T)
//   / (nItem[p]*nItem[q]); hA=x[p,q]@W1, hB=x[q,p]@W1 (bf16 MFMA in-block).
//
// Lessons r4-r10: staging regs + compute regs in one thread -> spill at the
// ~128-VGPR allocator wall; per-kc barrier pipelines convoy. Fix: split roles
// BY WAVE. 256 persistent blocks (1/CU) x 512 thr: waves 4-7 stage pair k+1
// into the spare LDS pair-buffer (regs ~70, absorb all HBM latency); waves
// 0-3 run r3's proj->h->score verbatim on pair k (never touch global x).
// LDS = 2 pair-buffers = 135 KiB. 4 matched barriers/pair.

#define NSET 64
#define MITEM 64
#define FFEAT 256
#define NPAIR 2080
#define NBLK 256

typedef float f32x4 __attribute__((ext_vector_type(4)));
typedef short bf16x8 __attribute__((ext_vector_type(8)));
typedef unsigned short u16;
typedef u16 u16x4 __attribute__((ext_vector_type(4)));

__device__ __forceinline__ u16 f2bf(float f) {
    __bf16 b = (__bf16)f;
    return __builtin_bit_cast(u16, b);
}
__device__ __forceinline__ f32x4 mfma16(bf16x8 a, bf16x8 b, f32x4 c) {
    return __builtin_amdgcn_mfma_f32_16x16x32_bf16(a, b, c, 0, 0, 0);
}
__device__ __forceinline__ void decode_pair(int idx, int& p, int& q) {
    p = 0;
    while (idx >= NSET - p) { idx -= NSET - p; ++p; }
    q = p + idx;
}

// ---- prep: W1 [k=256][c=256] f32 -> W1T bf16 [c][k] (B-frags contiguous in k)
__global__ void prep_w1t_kernel(const float* __restrict__ w1, u16* __restrict__ w1t) {
    int c = blockIdx.x, k = threadIdx.x;
    w1t[c * 256 + k] = f2bf(w1[k * 256 + c]);
}

// producer batch: 256 producer threads move half of both slices (16 float4 each).
// Coalesced: per instr one wave covers 1 KiB contiguous.
__device__ __forceinline__ void stage_batch(u16 (*DST)[MITEM][264],
                                            const float* __restrict__ xA,
                                            const float* __restrict__ xB,
                                            int pt, int half) {
    float4 ra[8], rb[8];
#pragma unroll
    for (int u = 0; u < 8; ++u) {
        const int f = (half * 8 + u) * 1024 + pt * 4;
        ra[u] = *(const float4*)(xA + f);
        rb[u] = *(const float4*)(xB + f);
    }
#pragma unroll
    for (int u = 0; u < 8; ++u) {
        const int f = (half * 8 + u) * 1024 + pt * 4;
        const int r = f >> 8, c = f & 255;
        u16x4 pa = { f2bf(ra[u].x), f2bf(ra[u].y), f2bf(ra[u].z), f2bf(ra[u].w) };
        u16x4 pb = { f2bf(rb[u].x), f2bf(rb[u].y), f2bf(rb[u].z), f2bf(rb[u].w) };
        *(u16x4*)&DST[0][r][c] = pa;
        *(u16x4*)&DST[1][r][c] = pb;
    }
}

__global__ __launch_bounds__(512, 1) void fused_kernel(const float* __restrict__ x,
                                                       const u16* __restrict__ w1t,
                                                       const float* __restrict__ nItem,
                                                       const float* __restrict__ W2,
                                                       float* __restrict__ out) {
    // [pair-buf][slice][64 rows][264 cols] bf16, 528 B stride. x then h in place.
    __shared__ u16 BUF[2][2][MITEM][264];   // 135.2 KiB
    __shared__ float red[4];

    const int tid  = threadIdx.x;
    const int lane = tid & 63;
    const int wave = tid >> 6;          // 0-3 consumer, 4-7 producer
    const int ar   = lane & 15;
    const int kg   = lane >> 4;
    const int k0   = kg * 8;

    const int bid = blockIdx.x;
    const int np  = (bid < 32) ? 9 : 8;   // 2080 = 8*256 + 32

    if (wave >= 4) {
        // ================= producer =================
        const int pt = tid - 256;
        {   // prologue: stage pair bid into BUF[0] (no barriers)
            int p, q; decode_pair(bid, p, q);
            const float* xA = x + (size_t)(p * NSET + q) * (MITEM * FFEAT);
            const float* xB = x + (size_t)(q * NSET + p) * (MITEM * FFEAT);
            stage_batch(BUF[0], xA, xB, pt, 0);
            stage_batch(BUF[0], xA, xB, pt, 1);
        }
        for (int k = 0; k < np; ++k) {
            __syncthreads();                       // (1) BUF[k&1] ready
            const int nk = k + 1;
            const bool have = nk < np;
            int p, q; decode_pair(have ? bid + nk * NBLK : bid, p, q);
            const float* xA = x + (size_t)(p * NSET + q) * (MITEM * FFEAT);
            const float* xB = x + (size_t)(q * NSET + p) * (MITEM * FFEAT);
            if (have) {                            // stage during consumer proj
                stage_batch(BUF[nk & 1], xA, xB, pt, 0);
                stage_batch(BUF[nk & 1], xA, xB, pt, 1);
            }
            __syncthreads();                       // (2) = consumer post-x-read
            __syncthreads();                       // (3) = consumer post-h-write
            __syncthreads();                       // (4) = consumer post-red
        }
    } else {
        // ================= consumer (r3 math verbatim) =================
        const int g = wave;                        // proj col-group == score head
        for (int k = 0; k < np; ++k) {
            __syncthreads();                       // (1) BUF[cb] staged
            const int cb = k & 1;
            int p, q; decode_pair(bid + k * NBLK, p, q);
            u16 (*BUFA)[264] = BUF[cb][0];
            u16 (*BUFB)[264] = BUF[cb][1];

            // ---- proj: wave owns 64-col group g of BOTH slices ----
            f32x4 accA[4][4] = {}, accB[4][4] = {};
#pragma unroll
            for (int kc = 0; kc < 8; ++kc) {
                bf16x8 bu[4], aA[4], aB[4];
#pragma unroll
                for (int u = 0; u < 4; ++u)
                    bu[u] = *(const bf16x8*)(w1t
                        + (size_t)(g * 64 + u * 16 + ar) * 256 + kc * 32 + k0);
#pragma unroll
                for (int rt = 0; rt < 4; ++rt) {
                    aA[rt] = *(const bf16x8*)&BUFA[rt * 16 + ar][kc * 32 + k0];
                    aB[rt] = *(const bf16x8*)&BUFB[rt * 16 + ar][kc * 32 + k0];
                }
#pragma unroll
                for (int u = 0; u < 4; ++u)
#pragma unroll
                    for (int rt = 0; rt < 4; ++rt) {
                        accA[rt][u] = mfma16(aA[rt], bu[u], accA[rt][u]);
                        accB[rt][u] = mfma16(aB[rt], bu[u], accB[rt][u]);
                    }
            }
            __syncthreads();                       // (2) all x reads done

            // ---- h write in place; C/D: col=lane&15, row=(lane>>4)*4+j [m89]
#pragma unroll
            for (int rt = 0; rt < 4; ++rt)
#pragma unroll
                for (int u = 0; u < 4; ++u) {
                    const int cc = g * 64 + u * 16 + ar;
#pragma unroll
                    for (int j = 0; j < 4; ++j) {
                        BUFA[rt * 16 + kg * 4 + j][cc] = f2bf(accA[rt][u][j]);
                        BUFB[rt * 16 + kg * 4 + j][cc] = f2bf(accB[rt][u][j]);
                    }
                }
            __syncthreads();                       // (3) h visible

            // ---- score head g: relu-sum of hA_g @ hB_g^T ----
            const int hc = g * 64;
            bf16x8 aS[4][2];
#pragma unroll
            for (int rt = 0; rt < 4; ++rt)
#pragma unroll
                for (int kk = 0; kk < 2; ++kk)
                    aS[rt][kk] = *(const bf16x8*)
                        &BUFA[rt * 16 + ar][hc + kk * 32 + k0];
            float sum = 0.f;
#pragma unroll
            for (int bu = 0; bu < 4; ++bu) {
                bf16x8 b0 = *(const bf16x8*)&BUFB[bu * 16 + ar][hc + k0];
                bf16x8 b1 = *(const bf16x8*)&BUFB[bu * 16 + ar][hc + 32 + k0];
#pragma unroll
                for (int rt = 0; rt < 4; ++rt) {
                    f32x4 c = {};
                    c = mfma16(aS[rt][0], b0, c);
                    c = mfma16(aS[rt][1], b1, c);   // full k=64 BEFORE relu
                    sum += fmaxf(c[0], 0.f) + fmaxf(c[1], 0.f) +
                           fmaxf(c[2], 0.f) + fmaxf(c[3], 0.f);
                }
            }
#pragma unroll
            for (int off = 32; off; off >>= 1) sum += __shfl_xor(sum, off);
            if (lane == 0) red[wave] = sum;
            __syncthreads();                       // (4) red visible
            if (tid == 0) {
                const float nP = nItem[p], nQ = nItem[q];
                float v = 0.f;
#pragma unroll
                for (int h = 0; h < 4; ++h)
                    v += (((red[h] * 0.125f) / nQ) / nP) * W2[h];
                out[p * NSET + q] = v;
                out[q * NSET + p] = v;
            }
        }
    }
}

extern "C" void kernel_launch(void* const* d_in, const int* in_sizes, int n_in,
                              void* d_out, int out_size, void* d_ws, size_t ws_size,
                              hipStream_t stream) {
    const float* x     = (const float*)d_in[0];
    const float* nItem = (const float*)d_in[1];
    const float* W1    = (const float*)d_in[2];
    const float* W2    = (const float*)d_in[3];
    float* out = (float*)d_out;

    u16* w1t = (u16*)d_ws;                 // 128 KiB
    if (ws_size < 131072) return;

    hipLaunchKernelGGL(prep_w1t_kernel, dim3(256), dim3(256), 0, stream, W1, w1t);
    hipLaunchKernelGGL(fused_kernel, dim3(NBLK), dim3(512), 0, stream,
                       x, w1t, nItem, W2, out);
}